// Round 15
// baseline (611.138 us; speedup 1.0000x reference)
//
#include <hip/hip_runtime.h>
#include <math.h>
#include <stddef.h>

#define NLAYER 24
#define NEMBD  1024
#define NFFN   4096
#define NB     256
#define NT     256            // waves 0-2 compute/stream; wave 3 polls
#define LN_EPS 1e-5f

#define OUT_SA (NEMBD)
#define OUT_SB (NEMBD + NLAYER*NEMBD)
#define OUT_SC (NEMBD + 2*NLAYER*NEMBD)
#define OUT_SD (NEMBD + 3*NLAYER*NEMBD)

typedef unsigned long long u64;
typedef unsigned u32;

// tagged-word queues (u64: tag<<32 | float bits); data IS the sync signal
#define QX_OFF    0        // 1024
#define QW_OFF    1024     // 1024
#define QSXX_OFF  2048     // 1024
#define QKFB_OFF  3072     // 4096
#define QTOTAL    7168

// LDS float offsets
#define LACT  0            // 4096: x(S1) / sxx(S3) / kf(S4)
#define LMSK  4096         // 3072: masks; w vector at S2
#define LPRM  7168         // 6144: params (6 slots, reused S1/S3)
#define LFF   13312        // 3 x 7168: FFN slabs (waves 0-2)
#define LKVR  34816        // 12: k,v,r dot results [mth*4+idx]
#define LLN   34828        // 8: LN partials
#define LXL   34836        // 4: x[b*4+r]
#define LSXL  34840        // 4: sxx[b*4+r]
#define LRFL  34844        // 4: rf[b*4+r]
#define LPT   34848        // 12: S4 partials [r*3+cw]
#define SMTOT 34860        // 139440 B

struct Params {
  const float *x, *state, *ln1w, *ln1b, *ln2w, *ln2b, *td, *tf, *kktk, *vvtv, *rrtr;
  const float *key, *outputv, *tmk, *tmr, *kffn, *rffn, *vffn;
  float *out;
  u64 *q;
};

__device__ __forceinline__ float wred(float v) {
#pragma unroll
  for (int o = 32; o > 0; o >>= 1) v += __shfl_xor(v, o, 64);
  return v;
}
__device__ __forceinline__ float dot4(float4 a, float4 b) {
  return a.x*b.x + a.y*b.y + a.z*b.z + a.w*b.w;
}
__device__ __forceinline__ u64 qload(const u64* a) {
  return __hip_atomic_load(a, __ATOMIC_RELAXED, __HIP_MEMORY_SCOPE_AGENT);
}
__device__ __forceinline__ void qput(u64* a, float v, u32 tag) {
  u64 w = ((u64)tag << 32) | (u64)__float_as_uint(v);
  __hip_atomic_store(a, w, __ATOMIC_RELAXED, __HIP_MEMORY_SCOPE_AGENT);
}
__device__ __forceinline__ u32   qtag(u64 w) { return (u32)(w >> 32); }
__device__ __forceinline__ float qval(u64 w) { return __uint_as_float((u32)w); }

// async global->LDS, 16B/lane
__device__ __forceinline__ void stage16(const float* g, float* l) {
  __builtin_amdgcn_global_load_lds(
      (const __attribute__((address_space(1))) unsigned int*)g,
      (__attribute__((address_space(3))) unsigned int*)l, 16, 0, 0);
}

// intra-block barrier: LDS ordering only; vmcnt untouched
__device__ __forceinline__ void lbar() {
  asm volatile("s_waitcnt lgkmcnt(0)" ::: "memory");
  __builtin_amdgcn_s_barrier();
  asm volatile("" ::: "memory");
}

// wave-3 poll: N words/lane (idx = c*64+lane), tag >= TG, stage to LDS
#define POLLS(N, QB, TG, LOFF)                                                \
  do {                                                                        \
    u64 pw_[N]; long cc_ = 0;                                                 \
    for (;;) {                                                                \
      bool ok_ = true;                                                        \
      _Pragma("unroll")                                                       \
      for (int c_ = 0; c_ < N; ++c_) pw_[c_] = qload((QB) + c_*64 + lane);    \
      _Pragma("unroll")                                                       \
      for (int c_ = 0; c_ < N; ++c_) ok_ &= (qtag(pw_[c_]) >= (TG));          \
      if (__all(ok_)) break;                                                  \
      __builtin_amdgcn_s_sleep(1);                                            \
      if (++cc_ > (1L << 20)) break;  /* safety: wrong beats hang */          \
    }                                                                         \
    _Pragma("unroll")                                                         \
    for (int c_ = 0; c_ < N; ++c_) sm[(LOFF) + c_*64 + lane] = qval(pw_[c_]); \
  } while (0)

__global__ void __launch_bounds__(NT, 1)
rwkv_persistent(Params p) {
  const int b    = blockIdx.x;
  const int t    = threadIdx.x;
  const int wid  = t >> 6;
  const int lane = t & 63;
  const int i0   = t * 4;
  const bool w3  = (wid == 3);
  const int cw   = wid;              // 0..2 compute waves

  __shared__ float sm[SMTOT];
  __shared__ unsigned genw_s;
  volatile unsigned* gw = &genw_s;

  if (t == 0) genw_s = 0u;
  __syncthreads();

  u64* QX   = p.q + QX_OFF;
  u64* QW   = p.q + QW_OFF;
  u64* QSXX = p.q + QSXX_OFF;
  u64* QKFB = p.q + QKFB_OFF;

  float4 wKEY[16];   // waves 0-2: method-cw key rows for 4 indices
  float4 wOV[4];     // waves 0-2: outputv row b*4+cw; wave 3: row b*4+3
  float4 wVF[24];    // waves 0-2: vffn 4 rows x 6/5/5 K-chunks
  float s_tf, s_sb, s_sc, s_td;   // wave-3 lanes<4 wkv scalars

  auto loadKEY = [&](int L) {      // method cw, indices 0..3
    const float* W = p.key + ((size_t)L * 3 + cw) * NEMBD * NEMBD
                   + (size_t)(b * 4) * NEMBD + lane * 4;
#pragma unroll
    for (int idx = 0; idx < 4; ++idx)
#pragma unroll
      for (int c = 0; c < 4; ++c)
        wKEY[idx * 4 + c] = *(const float4*)&W[(size_t)idx * NEMBD + c * 256];
  };
  auto loadOV = [&](int L, int row) {
    const float* W = p.outputv + ((size_t)L * NEMBD + b * 4 + row) * NEMBD + lane * 4;
#pragma unroll
    for (int c = 0; c < 4; ++c)
      wOV[c] = *(const float4*)&W[c * 256];
  };
  auto loadVF = [&](int L) {       // 4 rows x {6,5,5} K-chunks
    const int jb = (cw == 0) ? 0 : ((cw == 1) ? 6 : 11);
    const int jn = (cw == 0) ? 6 : 5;
#pragma unroll
    for (int r = 0; r < 4; ++r) {
      const float* W = p.vffn + ((size_t)L * NEMBD + b * 4 + r) * NFFN + lane * 4;
#pragma unroll
      for (int c = 0; c < 6; ++c) if (c < jn)
        wVF[r * 6 + c] = *(const float4*)&W[(jb + c) * 256];
    }
  };
  auto stageFF = [&](int L) {      // rows cw*7..cw*7+6 of [16 kffn | 4 rffn]
    float* slab = &sm[LFF + cw * 7168];
#pragma unroll
    for (int e = 0; e < 7; ++e) {
      const int f = cw * 7 + e;
      if (f < 20) {
        const float* W = (f < 16)
          ? p.kffn + ((size_t)L * NFFN  + b * 16 + f) * NEMBD
          : p.rffn + ((size_t)L * NEMBD + b * 4 + (f - 16)) * NEMBD;
#pragma unroll
        for (int c = 0; c < 4; ++c)
          stage16(W + c * 256 + lane * 4, slab + e * 1024 + c * 256);
      }
    }
  };
  auto stagePrm = [&](const float* src, int L, int v) {   // gl2lds, zero VGPR
#pragma unroll
    for (int c = 0; c < 4; ++c)
      stage16(src + L * NEMBD + c * 256 + lane * 4, &sm[LPRM + v * 1024 + c * 256]);
  };
  auto stagePA = [&](int L) {      // 2 vecs per compute wave
    if (cw == 0) { stagePrm(p.ln1w, L, 0); stagePrm(p.ln1b, L, 1); }
    if (cw == 1) { stagePrm(p.state + 0 * NLAYER * NEMBD, L, 2); stagePrm(p.kktk, L, 3); }
    if (cw == 2) { stagePrm(p.vvtv, L, 4); stagePrm(p.rrtr, L, 5); }
  };
  auto stagePC = [&](int L) {
    if (cw == 0) { stagePrm(p.ln2w, L, 0); stagePrm(p.ln2b, L, 1); }
    if (cw == 1) { stagePrm(p.state + 3 * NLAYER * NEMBD, L, 2); stagePrm(p.tmk, L, 3); }
    if (cw == 2) { stagePrm(p.tmr, L, 4); }
  };
  auto spin = [&](unsigned v) {    // compute waves: LDS spin, then productive drain
    long c = 0;
    while (*gw < v) { __builtin_amdgcn_s_sleep(1); if (++c > (1L << 20)) break; }
    asm volatile("" ::: "memory");
    asm volatile("s_waitcnt vmcnt(0)" ::: "memory");
  };
  auto post = [&](unsigned v) {    // wave 3: publish generation
    asm volatile("s_waitcnt lgkmcnt(0)" ::: "memory");
    if (lane == 0) *gw = v;
  };

  if (!w3) { loadKEY(0); loadOV(0, cw); stagePA(0); }   // prologue

  for (int l = 0; l < NLAYER; ++l) {
    const u32 t1 = (u32)(4 * l + 1), t2 = t1 + 1, t3 = t1 + 2, t4 = t1 + 3;
    const u32 g1 = (u32)(4 * l + 1), g2 = g1 + 1, g3 = g1 + 2, g4 = g1 + 3;

    // ===== STAGE 1: x -> ln1 -> masks -> key dots -> wkv (wave 3) =====
    if (w3) {
      if (l == 0) {
#pragma unroll
        for (int c = 0; c < 4; ++c) {
          float4 xv = *(const float4*)&p.x[c * 256 + lane * 4];
          *(float4*)&sm[LACT + c * 256 + lane * 4] = xv;
        }
      } else {
        POLLS(16, QX, (u32)(4 * l), LACT);
      }
      if (lane < 4) {                      // wkv scalars for idx=lane
        const int ix = l * NEMBD + b * 4 + lane;
        s_tf = p.tf[ix];
        s_sb = p.state[1 * NLAYER * NEMBD + ix];
        s_sc = p.state[2 * NLAYER * NEMBD + ix];
        s_td = p.td[ix];
      }
      loadOV(l, 3);                        // its own S2 row
      post(g1);
    } else {
      spin(g1);                            // weights stream during this spin
    }
    {
      float xa[4];
#pragma unroll
      for (int j = 0; j < 4; ++j) xa[j] = sm[LACT + i0 + j];
      float s = xa[0] + xa[1] + xa[2] + xa[3];
      float q = xa[0]*xa[0] + xa[1]*xa[1] + xa[2]*xa[2] + xa[3]*xa[3];
      s = wred(s); q = wred(q);
      if (lane == 0) { sm[LLN + wid] = s; sm[LLN + 4 + wid] = q; }
      lbar();
      float m  = (sm[LLN+0] + sm[LLN+1] + sm[LLN+2] + sm[LLN+3]) * (1.f / NEMBD);
      float tq = (sm[LLN+4] + sm[LLN+5] + sm[LLN+6] + sm[LLN+7]) * (1.f / NEMBD);
      float rs = rsqrtf(tq - m * m + LN_EPS);
#pragma unroll
      for (int j = 0; j < 4; ++j) {
        int i = i0 + j;
        float xy  = (xa[j] - m) * rs * sm[LPRM + i] + sm[LPRM + 1024 + i];
        float sav = sm[LPRM + 2048 + i];
        sm[LMSK + i]        = xy + sm[LPRM + 3072 + i] * sav;
        sm[LMSK + 1024 + i] = xy + sm[LPRM + 4096 + i] * sav;
        sm[LMSK + 2048 + i] = xy + sm[LPRM + 5120 + i] * sav;
        if (t == b) p.out[OUT_SA + l * NEMBD + i] = xy;   // statea
      }
      if (t == b) {
#pragma unroll
        for (int j = 0; j < 4; ++j) sm[LXL + j] = xa[j];
      }
      lbar();                              // masks ready
      if (!w3) {
        const float* mv = &sm[LMSK + cw * 1024];   // method-cw mask
#pragma unroll
        for (int idx = 0; idx < 4; ++idx) {
          float a = 0.f;
#pragma unroll
          for (int c = 0; c < 4; ++c)
            a += dot4(wKEY[idx * 4 + c], *(const float4*)&mv[lane * 4 + c * 256]);
          a = wred(a);
          if (lane == 0) sm[LKVR + cw * 4 + idx] = a;
        }
      }
      lbar();                              // kvr ready
      if (w3 && lane < 4) {                // producer-side wkv combine
        float k = sm[LKVR + lane], v = sm[LKVR + 4 + lane], r = sm[LKVR + 8 + lane];
        float etfk = expf(s_tf + k);
        float er   = expf(r);
        // sc*er + exp(tf+k+r) + sc + etfk == (sc+etfk)*(1+er)
        float wv = (s_sb + etfk * v) / ((s_sc + etfk) * (1.f + er));
        qput(&QW[b * 4 + lane], wv, t1);
        float ek = expf(k), ed = expf(s_td);
        p.out[OUT_SB + l * NEMBD + b * 4 + lane] = s_sb * ed + ek * v;
        p.out[OUT_SC + l * NEMBD + b * 4 + lane] = s_sc * ed + ek;
      }
    }

    // ===== STAGE 2: w -> outputv dots -> sxx =====
    if (w3) {
      POLLS(16, QW, t1, LMSK);
      post(g2);
      float a = 0.f;                       // its own row b*4+3
#pragma unroll
      for (int c = 0; c < 4; ++c)
        a += dot4(wOV[c], *(const float4*)&sm[LMSK + lane * 4 + c * 256]);
      a = wred(a);
      if (lane == 0) {
        float sxx = sm[LXL + 3] + a;
        qput(&QSXX[b * 4 + 3], sxx, t2);
        sm[LSXL + 3] = sxx;
      }
    } else {
      spin(g2);                            // nothing outstanding: free
      float a = 0.f;
#pragma unroll
      for (int c = 0; c < 4; ++c)
        a += dot4(wOV[c], *(const float4*)&sm[LMSK + lane * 4 + c * 256]);
      a = wred(a);
      if (lane == 0) {
        float sxx = sm[LXL + cw] + a;
        qput(&QSXX[b * 4 + cw], sxx, t2);
        sm[LSXL + cw] = sxx;
      }
      stageFF(l); stagePC(l);              // S3 bundle -> streams into S3
    }

    // ===== STAGE 3: sxx -> ln2 -> masks -> ffn dots (LDS slabs) =====
    if (w3) {
      POLLS(16, QSXX, t2, LACT);
      post(g3);
    } else {
      spin(g3);                            // drains FF+pC: productive
    }
    {
      float xa[4];
#pragma unroll
      for (int j = 0; j < 4; ++j) xa[j] = sm[LACT + i0 + j];
      float s = xa[0] + xa[1] + xa[2] + xa[3];
      float q = xa[0]*xa[0] + xa[1]*xa[1] + xa[2]*xa[2] + xa[3]*xa[3];
      s = wred(s); q = wred(q);
      if (lane == 0) { sm[LLN + wid] = s; sm[LLN + 4 + wid] = q; }
      lbar();
      float m  = (sm[LLN+0] + sm[LLN+1] + sm[LLN+2] + sm[LLN+3]) * (1.f / NEMBD);
      float tq = (sm[LLN+4] + sm[LLN+5] + sm[LLN+6] + sm[LLN+7]) * (1.f / NEMBD);
      float rs = rsqrtf(tq - m * m + LN_EPS);
#pragma unroll
      for (int j = 0; j < 4; ++j) {
        int i = i0 + j;
        float xx  = (xa[j] - m) * rs * sm[LPRM + i] + sm[LPRM + 1024 + i];
        float sdv = sm[LPRM + 2048 + i];
        sm[LMSK + i]        = xx + sm[LPRM + 3072 + i] * sdv;
        sm[LMSK + 1024 + i] = xx + sm[LPRM + 4096 + i] * sdv;
        if (t == b) p.out[OUT_SD + l * NEMBD + i] = xx;   // stated
      }
      lbar();                              // masks ready
      if (!w3) {
        const float* slab = &sm[LFF + cw * 7168];
#pragma unroll
        for (int e = 0; e < 7; ++e) {
          const int f = cw * 7 + e;
          if (f < 20) {
            const float* mv = &sm[LMSK + ((f < 16) ? 0 : 1024)];
            float a = 0.f;
#pragma unroll
            for (int c = 0; c < 4; ++c) {
              int col = lane * 4 + c * 256;
              a += dot4(*(const float4*)&slab[e * 1024 + col],
                        *(const float4*)&mv[col]);
            }
            a = wred(a);
            if (lane == 0) {
              if (f < 16) { float kv = fmaxf(a, 0.f); qput(&QKFB[b * 16 + f], kv * kv, t3); }
              else        { sm[LRFL + (f - 16)] = expf(a); }
            }
          }
        }
        loadVF(l);                         // S4 bundle
      }
    }

    // ===== STAGE 4: kf -> vffn dots (K-split) -> x' =====
    if (w3) {
      POLLS(32, QKFB, t3, LACT);
      POLLS(32, QKFB + 2048, t3, LACT + 2048);
      post(g4);
    } else {
      spin(g4);                            // drains VF: productive
      const int jb = (cw == 0) ? 0 : ((cw == 1) ? 6 : 11);
      const int jn = (cw == 0) ? 6 : 5;
#pragma unroll
      for (int r = 0; r < 4; ++r) {
        float a = 0.f;
#pragma unroll
        for (int c = 0; c < 6; ++c) if (c < jn)
          a += dot4(wVF[r * 6 + c],
                    *(const float4*)&sm[LACT + lane * 4 + (jb + c) * 256]);
        a = wred(a);
        if (lane == 0) sm[LPT + r * 3 + cw] = a;
      }
      if (l + 1 < NLAYER) { loadKEY(l + 1); loadOV(l + 1, cw); stagePA(l + 1); }
    }
    lbar();                                // partials ready
    if (w3 && lane < 4) {
      float tot = sm[LPT + lane * 3] + sm[LPT + lane * 3 + 1] + sm[LPT + lane * 3 + 2];
      float xn  = sm[LSXL + lane] + tot / (sm[LRFL + lane] + 1.f);
      if (l == NLAYER - 1) p.out[b * 4 + lane] = xn;     // final x_out
      else                 qput(&QX[b * 4 + lane], xn, t4);
    }
  }
}

__global__ void rwkv_init(u64* q) {
  for (int i = 0; i < 28; ++i)
    q[threadIdx.x * 28 + i] = 0ull;
}

extern "C" void kernel_launch(void* const* d_in, const int* in_sizes, int n_in,
                              void* d_out, int out_size, void* d_ws, size_t ws_size,
                              hipStream_t stream) {
  Params p;
  p.x       = (const float*)d_in[0];
  p.state   = (const float*)d_in[1];
  p.ln1w    = (const float*)d_in[2];
  p.ln1b    = (const float*)d_in[3];
  p.ln2w    = (const float*)d_in[4];
  p.ln2b    = (const float*)d_in[5];
  p.td      = (const float*)d_in[6];
  p.tf      = (const float*)d_in[7];
  p.kktk    = (const float*)d_in[8];
  p.vvtv    = (const float*)d_in[9];
  p.rrtr    = (const float*)d_in[10];
  p.key     = (const float*)d_in[11];
  p.outputv = (const float*)d_in[12];
  p.tmk     = (const float*)d_in[13];
  p.tmr     = (const float*)d_in[14];
  p.kffn    = (const float*)d_in[15];
  p.rffn    = (const float*)d_in[16];
  p.vffn    = (const float*)d_in[17];
  p.out     = (float*)d_out;
  p.q       = (u64*)d_ws;            // 7168 u64 = 57344 B

  rwkv_init<<<1, NB, 0, stream>>>(p.q);
  rwkv_persistent<<<NB, NT, 0, stream>>>(p);
}